// Round 2
// baseline (690.290 us; speedup 1.0000x reference)
//
#include <hip/hip_runtime.h>

#define NN 10000
#define FF 64
#define HH 128
#define EE 640000
#define CC 100

// ---------------- BatchNorm stats: scale/shift per feature ----------------
__global__ __launch_bounds__(256) void k_bn_stats(
    const float* __restrict__ x, const float* __restrict__ gamma,
    const float* __restrict__ beta, float* __restrict__ scale, float* __restrict__ shift){
  int f = blockIdx.x, t = threadIdx.x;
  double s = 0.0, s2 = 0.0;
  for (int r = t; r < NN; r += 256){ float v = x[r*FF + f]; s += v; s2 += (double)v * v; }
  #pragma unroll
  for (int o = 32; o > 0; o >>= 1){ s += __shfl_down(s, o); s2 += __shfl_down(s2, o); }
  __shared__ double ls[4], ls2[4];
  if ((t & 63) == 0){ ls[t >> 6] = s; ls2[t >> 6] = s2; }
  __syncthreads();
  if (t == 0){
    double S  = ls[0]+ls[1]+ls[2]+ls[3];
    double S2 = ls2[0]+ls2[1]+ls2[2]+ls2[3];
    double mu = S / NN;
    double var = S2 / NN - mu*mu;
    double sc = (double)gamma[f] / sqrt(var + 1e-5);
    scale[f] = (float)sc;
    shift[f] = (float)((double)beta[f] - mu*sc);
  }
}

// ---------------- CSR build: histogram, scan, scatter ----------------
__global__ __launch_bounds__(256) void k_hist(const int* __restrict__ rows, int* __restrict__ counts){
  int e = blockIdx.x*256 + threadIdx.x;
  if (e < EE) atomicAdd(&counts[rows[e]], 1);
}

__global__ __launch_bounds__(256) void k_scan(const int* __restrict__ counts,
    int* __restrict__ offs, int* __restrict__ curs){
  __shared__ int part[256];
  int t = threadIdx.x;
  int base = t*40;
  int s = 0;
  for (int i=0;i<40;i++){ int idx=base+i; if (idx<NN) s += counts[idx]; }
  part[t] = s;
  __syncthreads();
  for (int o=1;o<256;o<<=1){
    int v = (t>=o)? part[t-o] : 0;
    __syncthreads();
    part[t] += v;
    __syncthreads();
  }
  int run = (t==0)? 0 : part[t-1];
  for (int i=0;i<40;i++){ int idx=base+i; if (idx<NN){ offs[idx]=run; curs[idx]=run; run += counts[idx]; } }
  if (t==255) offs[NN] = part[255];
}

__global__ __launch_bounds__(256) void k_scatter(const int* __restrict__ rows, const int* __restrict__ cols,
    const float* __restrict__ nvals, int* __restrict__ curs,
    int* __restrict__ cols_s, float* __restrict__ vals_s){
  int e = blockIdx.x*256 + threadIdx.x;
  if (e < EE){
    int r = rows[e];
    int pos = atomicAdd(&curs[r], 1);
    cols_s[pos] = cols[e];
    vals_s[pos] = nvals[e];
  }
}

// ---------------- SpMM (wave per row, lane = feature) ----------------
__global__ __launch_bounds__(256) void k_spmm_bn(
    const int* __restrict__ offs, const int* __restrict__ cols_s, const float* __restrict__ vals_s,
    const float* __restrict__ xin, const float* __restrict__ scale, const float* __restrict__ shift,
    float* __restrict__ xout){
  int lane = threadIdx.x & 63;
  int r = blockIdx.x*4 + (threadIdx.x >> 6);
  float sc = scale[lane], sh = shift[lane];
  int b = offs[r], e = offs[r+1];
  float acc = 0.f;
  for (int j = b; j < e; ++j){
    int c = cols_s[j]; float v = vals_s[j];
    acc += v * (xin[c*FF + lane]*sc + sh);   // BN fused into gather
  }
  xout[r*FF + lane] = acc;
}

__global__ __launch_bounds__(256) void k_spmm(
    const int* __restrict__ offs, const int* __restrict__ cols_s, const float* __restrict__ vals_s,
    const float* __restrict__ xin, float* __restrict__ xout){
  int lane = threadIdx.x & 63;
  int r = blockIdx.x*4 + (threadIdx.x >> 6);
  int b = offs[r], e = offs[r+1];
  float acc = 0.f;
  for (int j = b; j < e; ++j){
    int c = cols_s[j];
    acc += vals_s[j] * xin[c*FF + lane];
  }
  xout[r*FF + lane] = acc;
}

// ---------------- s0 = softmax(relu(x_cov@W1+b1)@W2+b2) ----------------
__global__ __launch_bounds__(256) void k_s0(
    const float* __restrict__ xcov,
    const float* __restrict__ W1, const float* __restrict__ b1,
    const float* __restrict__ W2, const float* __restrict__ b2,
    float* __restrict__ s0){
  __shared__ float xs[32][FF];
  __shared__ float hs[32][HH];
  __shared__ float lsm[32][CC];
  __shared__ float chunk[32*HH];
  __shared__ float rsum[32];
  int t = threadIdx.x; int r0 = blockIdx.x*32;
  for (int i=t;i<32*FF;i+=256){ int r=i>>6, f=i&63; int gr=r0+r; xs[r][f] = (gr<NN)? xcov[gr*FF+f] : 0.f; }
  __syncthreads();
  { // h = relu(x@W1+b1): each thread owns column j, 16 rows (stride 2)
    int j = t & 127;
    float acc[16]; float bb = b1[j];
    #pragma unroll
    for (int p=0;p<16;p++) acc[p] = bb;
    for (int kc=0;kc<2;kc++){
      for (int i=t;i<32*HH;i+=256) chunk[i] = W1[(kc*32 + (i>>7))*HH + (i&127)];
      __syncthreads();
      #pragma unroll
      for (int p=0;p<16;p++){
        int r = (t>>7) + 2*p;
        float a = acc[p];
        #pragma unroll
        for (int k=0;k<32;k++) a += xs[r][kc*32+k]*chunk[k*HH + j];
        acc[p] = a;
      }
      __syncthreads();
    }
    #pragma unroll
    for (int p=0;p<16;p++){ int r=(t>>7)+2*p; hs[r][j] = fmaxf(acc[p], 0.f); }
  }
  __syncthreads();
  { // logits = h@W2+b2 (K chunked through LDS)
    float acc[13];
    #pragma unroll
    for (int p=0;p<13;p++){ int i=p*256+t; acc[p] = (i<3200)? b2[i % CC] : 0.f; }
    for (int kc=0;kc<4;kc++){
      for (int i=t;i<32*CC;i+=256) chunk[i] = W2[(kc*32 + i/CC)*CC + (i % CC)];
      __syncthreads();
      #pragma unroll
      for (int p=0;p<13;p++){
        int i = p*256+t;
        if (i < 32*CC){
          int r = i/CC, j = i - r*CC;
          float a = acc[p];
          #pragma unroll
          for (int k=0;k<32;k++) a += hs[r][kc*32+k]*chunk[k*CC + j];
          acc[p] = a;
        }
      }
      __syncthreads();
    }
    #pragma unroll
    for (int p=0;p<13;p++){ int i=p*256+t; if (i<32*CC){ int r=i/CC, j=i-r*CC; lsm[r][j]=acc[p]; } }
  }
  __syncthreads();
  if (t < 32){
    float m = -1e30f;
    for (int j=0;j<CC;j++) m = fmaxf(m, lsm[t][j]);
    float s = 0.f;
    for (int j=0;j<CC;j++){ float e = expf(lsm[t][j]-m); lsm[t][j]=e; s += e; }
    rsum[t] = s;
  }
  __syncthreads();
  for (int i=t;i<32*CC;i+=256){ int r=i/CC, j=i-r*CC; int gr=r0+r; if (gr<NN) s0[gr*CC + j] = lsm[r][j]/rsum[r]; }
}

// ---------------- x_cov1 = s0^T @ x_cov (partials + atomic finish) ----------------
__global__ __launch_bounds__(256) void k_xcov1(
    const float* __restrict__ s0, const float* __restrict__ xcov, float* __restrict__ xc1){
  __shared__ float srow[4][CC];
  __shared__ float xrow[4][FF];
  int t = threadIdx.x;
  int rbase = blockIdx.x * 100;     // 100 blocks x 100 rows
  int f = t & 63, cb = (t>>6)*25;   // thread owns (c in [cb,cb+25), fixed f)
  float acc[25];
  #pragma unroll
  for (int i=0;i<25;i++) acc[i]=0.f;
  for (int step=0; step<25; ++step){
    int rr0 = rbase + step*4;
    for (int i=t;i<4*CC;i+=256){ int rr=i/CC; srow[rr][i - rr*CC] = s0[(rr0+rr)*CC + (i - rr*CC)]; }
    for (int i=t;i<4*FF;i+=256){ int rr=i>>6; xrow[rr][i&63] = xcov[(rr0+rr)*FF + (i&63)]; }
    __syncthreads();
    #pragma unroll
    for (int rr=0;rr<4;rr++){
      float xv = xrow[rr][f];
      #pragma unroll
      for (int i=0;i<25;i++) acc[i] += srow[rr][cb+i]*xv;
    }
    __syncthreads();
  }
  #pragma unroll
  for (int i=0;i<25;i++) atomicAdd(&xc1[(cb+i)*FF + f], acc[i]);
}

// ---------------- gv[f] = 2*sigmoid(fc[f] - colsum(x_cov1)[f]) ----------------
__global__ void k_gv(const float* __restrict__ xc1, const float* __restrict__ fc, float* __restrict__ gv){
  int f = threadIdx.x; // 64 threads
  float s = 0.f;
  for (int c=0;c<CC;c++) s += xc1[c*FF + f];
  float z = fc[f] - s;
  gv[f] = 2.f / (1.f + expf(-z));
}

// ---------------- adjs: dot + sequential cumprod + LDS-transposed float4 write ----------------
__global__ __launch_bounds__(256) void k_adjs(
    const int* __restrict__ rows, const int* __restrict__ cols,
    const float* __restrict__ adjv, const float* __restrict__ s0,
    const float* __restrict__ gv, float* __restrict__ out){
  __shared__ float gvs[64];
  __shared__ int   rs[256], cs[256];
  __shared__ float dotbuf[256];
  __shared__ float buf[16*258];     // [feature][edge+pad]: writes conflict-free, reads 2-way (free)
  int t = threadIdx.x;
  int e0 = blockIdx.x*256;
  rs[t] = rows[e0+t]; cs[t] = cols[e0+t];
  if (t < 64) gvs[t] = gv[t];
  __syncthreads();
  // phase 1: cooperative dots (16 lanes per edge, float2 -> coalesced s0 reads)
  int gid = t>>4, lane = t&15;
  for (int it=0; it<16; ++it){
    int ed = gid*16 + it;
    int r = rs[ed], c = cs[ed];
    const float2* sr = (const float2*)(s0 + (size_t)r*CC);   // 400B row base: 8B aligned
    const float2* sc2 = (const float2*)(s0 + (size_t)c*CC);
    float p = 0.f;
    #pragma unroll
    for (int k=0;k<4;k++){
      int cc2 = k*16 + lane;           // float2 index; 50 float2 = 100 floats
      if (cc2 < 50){
        float2 a = sr[cc2], b = sc2[cc2];
        p += a.x*b.x + a.y*b.y;
      }
    }
    #pragma unroll
    for (int o=1;o<16;o<<=1) p += __shfl_xor(p, o);
    if (lane==0) dotbuf[ed] = p;
  }
  __syncthreads();
  // phase 2: per-edge sequential cumprod (matches reference rounding/underflow),
  // LDS transpose, fully-coalesced float4 stores (16B lanes -> aligned 64B segments)
  float dot = dotbuf[t];
  float adj = adjv[e0+t];
  float cum = 1.f;
  float4* out4 = (float4*)out;
  size_t obase4 = (size_t)e0*16;      // e0*64 floats / 4
  for (int ch=0; ch<4; ++ch){
    #pragma unroll
    for (int j=0;j<16;j++){
      cum *= dot * gvs[ch*16+j];
      buf[j*258 + t] = adj*cum;
    }
    __syncthreads();
    #pragma unroll
    for (int i=0;i<4;i++){
      int id = i*256 + t;             // 1024 float4 per chunk
      int el = id >> 2, f4 = id & 3;
      float4 v;
      v.x = buf[(f4*4+0)*258 + el];
      v.y = buf[(f4*4+1)*258 + el];
      v.z = buf[(f4*4+2)*258 + el];
      v.w = buf[(f4*4+3)*258 + el];
      out4[obase4 + (size_t)el*16 + ch*4 + f4] = v;
    }
    __syncthreads();
  }
}

// ---------------- MLP + log_softmax ----------------
__global__ __launch_bounds__(256) void k_mlp(
    const float* __restrict__ xin,
    const float* __restrict__ W1, const float* __restrict__ b1,
    const float* __restrict__ W2, const float* __restrict__ b2,
    const float* __restrict__ W3, const float* __restrict__ b3,
    const float* __restrict__ pa, float* __restrict__ out){
  __shared__ float xs[32][FF];
  __shared__ float h1[32][HH];
  __shared__ float h2[32][HH];
  __shared__ float chunk[32*HH];
  __shared__ float lg[32][2];
  int t = threadIdx.x; int r0 = blockIdx.x*32;
  float a0 = pa[0];
  for (int i=t;i<32*FF;i+=256){ int r=i>>6,f=i&63; int gr=r0+r; xs[r][f]=(gr<NN)? xin[gr*FF+f] : 0.f; }
  __syncthreads();
  { // h1 = prelu(x@W1+b1)
    int j = t & 127;
    float acc[16]; float bb=b1[j];
    #pragma unroll
    for (int p=0;p<16;p++) acc[p]=bb;
    for (int kc=0;kc<2;kc++){
      for (int i=t;i<32*HH;i+=256) chunk[i]=W1[(kc*32+(i>>7))*HH+(i&127)];
      __syncthreads();
      #pragma unroll
      for (int p=0;p<16;p++){ int r=(t>>7)+2*p; float a=acc[p];
        #pragma unroll
        for (int k=0;k<32;k++) a += xs[r][kc*32+k]*chunk[k*HH+j];
        acc[p]=a; }
      __syncthreads();
    }
    #pragma unroll
    for (int p=0;p<16;p++){ int r=(t>>7)+2*p; float v=acc[p]; h1[r][j] = v>0.f? v : a0*v; }
  }
  __syncthreads();
  { // h2 = prelu(h1@W2+b2)
    int j = t & 127;
    float acc[16]; float bb=b2[j];
    #pragma unroll
    for (int p=0;p<16;p++) acc[p]=bb;
    for (int kc=0;kc<4;kc++){
      for (int i=t;i<32*HH;i+=256) chunk[i]=W2[(kc*32+(i>>7))*HH+(i&127)];
      __syncthreads();
      #pragma unroll
      for (int p=0;p<16;p++){ int r=(t>>7)+2*p; float a=acc[p];
        #pragma unroll
        for (int k=0;k<32;k++) a += h1[r][kc*32+k]*chunk[k*HH+j];
        acc[p]=a; }
      __syncthreads();
    }
    #pragma unroll
    for (int p=0;p<16;p++){ int r=(t>>7)+2*p; float v=acc[p]; h2[r][j] = v>0.f? v : a0*v; }
  }
  __syncthreads();
  if (t < 64){
    int cls = t & 1, r = t >> 1;
    float acc = b3[cls];
    #pragma unroll
    for (int k=0;k<HH;k++){
      int kk = (k + r) & 127;          // swizzle: avoid 32-way LDS bank conflict (stride 512B)
      acc += h2[r][kk]*W3[kk*2+cls];
    }
    lg[r][cls] = acc;
  }
  __syncthreads();
  if (t < 32){
    int gr = r0 + t;
    if (gr < NN){
      float l0=lg[t][0], l1=lg[t][1];
      float m = fmaxf(l0,l1);
      float lse = m + logf(expf(l0-m)+expf(l1-m));
      out[gr*2+0] = l0 - lse;
      out[gr*2+1] = l1 - lse;
    }
  }
}

extern "C" void kernel_launch(void* const* d_in, const int* in_sizes, int n_in,
                              void* d_out, int out_size, void* d_ws, size_t ws_size,
                              hipStream_t stream) {
  (void)in_sizes; (void)n_in; (void)out_size; (void)ws_size;
  const float* x      = (const float*)d_in[0];
  const float* xcov   = (const float*)d_in[1];
  const int*   ei     = (const int*)d_in[2];
  const float* adjv   = (const float*)d_in[3];
  const float* nvals  = (const float*)d_in[4];
  const float* fc     = (const float*)d_in[5];
  const float* gamma  = (const float*)d_in[6];
  const float* beta   = (const float*)d_in[7];
  const float* p0W1   = (const float*)d_in[8];
  const float* p0b1   = (const float*)d_in[9];
  const float* p0W2   = (const float*)d_in[10];
  const float* p0b2   = (const float*)d_in[11];
  // d_in[12..15]: pool1 weights — mathematically dead (softmax over 1 class == 1)
  const float* mW1    = (const float*)d_in[16];
  const float* mb1    = (const float*)d_in[17];
  const float* mW2    = (const float*)d_in[18];
  const float* mb2    = (const float*)d_in[19];
  const float* mW3    = (const float*)d_in[20];
  const float* mb3    = (const float*)d_in[21];
  const float* pa     = (const float*)d_in[22];
  const int* rows = ei;
  const int* cols = ei + EE;
  float* out = (float*)d_out;

  char* w = (char*)d_ws;
  auto alloc = [&](size_t bytes)->void*{ void* p=(void*)w; w += (bytes + 255) & ~(size_t)255; return p; };
  float* S0    = (float*)alloc(sizeof(float)*(size_t)NN*CC);   // 4 MB
  float* XC1   = (float*)alloc(sizeof(float)*CC*FF);
  float* GV    = (float*)alloc(sizeof(float)*FF);
  float* SCALE = (float*)alloc(sizeof(float)*FF);
  float* SHIFT = (float*)alloc(sizeof(float)*FF);
  float* XA    = (float*)alloc(sizeof(float)*(size_t)NN*FF);
  float* XB    = (float*)alloc(sizeof(float)*(size_t)NN*FF);
  int*   COUNTS= (int*)alloc(sizeof(int)*NN);
  int*   OFFS  = (int*)alloc(sizeof(int)*(NN+1));
  int*   CURS  = (int*)alloc(sizeof(int)*NN);
  int*   COLS_S= (int*)alloc(sizeof(int)*EE);
  float* VALS_S= (float*)alloc(sizeof(float)*EE);

  hipMemsetAsync(COUNTS, 0, sizeof(int)*NN, stream);
  hipMemsetAsync(XC1, 0, sizeof(float)*CC*FF, stream);

  k_bn_stats<<<FF, 256, 0, stream>>>(x, gamma, beta, SCALE, SHIFT);
  k_hist<<<EE/256, 256, 0, stream>>>(rows, COUNTS);
  k_scan<<<1, 256, 0, stream>>>(COUNTS, OFFS, CURS);
  k_scatter<<<EE/256, 256, 0, stream>>>(rows, cols, nvals, CURS, COLS_S, VALS_S);

  k_s0<<<(NN+31)/32, 256, 0, stream>>>(xcov, p0W1, p0b1, p0W2, p0b2, S0);
  k_xcov1<<<100, 256, 0, stream>>>(S0, xcov, XC1);
  k_gv<<<1, 64, 0, stream>>>(XC1, fc, GV);
  k_adjs<<<EE/256, 256, 0, stream>>>(rows, cols, adjv, S0, GV, out + 2*NN);

  k_spmm_bn<<<NN/4, 256, 0, stream>>>(OFFS, COLS_S, VALS_S, x, SCALE, SHIFT, XA);
  k_spmm   <<<NN/4, 256, 0, stream>>>(OFFS, COLS_S, VALS_S, XA, XB);
  k_spmm   <<<NN/4, 256, 0, stream>>>(OFFS, COLS_S, VALS_S, XB, XA);

  k_mlp<<<(NN+31)/32, 256, 0, stream>>>(XA, mW1, mb1, mW2, mb2, mW3, mb3, pa, out);
}

// Round 6
// 565.653 us; speedup vs baseline: 1.2203x; 1.2203x over previous
//
#include <hip/hip_runtime.h>

#define NN 10000
#define FF 64
#define HH 128
#define EE 640000
#define CC 100

// ---------------- BatchNorm stats: coalesced two-pass (deterministic) ----------------
__global__ __launch_bounds__(256) void k_bn_partial(
    const float* __restrict__ x, double* __restrict__ part){
  __shared__ double ds[4][64], d2[4][64];
  int t = threadIdx.x; int f = t & 63, g = t >> 6;
  size_t base = (size_t)blockIdx.x * 6400;   // 100 rows x 64 feats per block
  double s = 0.0, s2 = 0.0;
  #pragma unroll
  for (int i = 0; i < 25; i++){ float v = x[base + i*256 + t]; s += v; s2 += (double)v * v; }
  ds[g][f] = s; d2[g][f] = s2;
  __syncthreads();
  if (t < 64){
    double S  = ds[0][t]+ds[1][t]+ds[2][t]+ds[3][t];
    double S2 = d2[0][t]+d2[1][t]+d2[2][t]+d2[3][t];
    part[blockIdx.x*128 + t]      = S;
    part[blockIdx.x*128 + 64 + t] = S2;
  }
}

__global__ void k_bn_finish(const double* __restrict__ part,
    const float* __restrict__ gamma, const float* __restrict__ beta,
    float* __restrict__ scale, float* __restrict__ shift){
  int f = threadIdx.x;   // 64 threads
  double S = 0.0, S2 = 0.0;
  for (int b = 0; b < 100; b++){ S += part[b*128 + f]; S2 += part[b*128 + 64 + f]; }
  double mu = S / NN;
  double var = S2 / NN - mu*mu;
  double sc = (double)gamma[f] / sqrt(var + 1e-5);
  scale[f] = (float)sc;
  shift[f] = (float)((double)beta[f] - mu*sc);
}

// ---------------- CSR build: histogram, scan, scatter ----------------
__global__ __launch_bounds__(256) void k_hist(const int* __restrict__ rows, int* __restrict__ counts){
  int e = blockIdx.x*256 + threadIdx.x;
  if (e < EE) atomicAdd(&counts[rows[e]], 1);
}

__global__ __launch_bounds__(1024) void k_scan(const int* __restrict__ counts,
    int* __restrict__ offs, int* __restrict__ curs){
  __shared__ int part[1024];
  int t = threadIdx.x;
  int base = t*10;
  int s = 0;
  #pragma unroll
  for (int i=0;i<10;i++){ int idx=base+i; if (idx<NN) s += counts[idx]; }
  part[t] = s;
  __syncthreads();
  for (int o=1;o<1024;o<<=1){
    int v = (t>=o)? part[t-o] : 0;
    __syncthreads();
    part[t] += v;
    __syncthreads();
  }
  int run = (t==0)? 0 : part[t-1];
  #pragma unroll
  for (int i=0;i<10;i++){ int idx=base+i; if (idx<NN){ offs[idx]=run; curs[idx]=run; run += counts[idx]; } }
  if (t==1023) offs[NN] = part[1023];
}

__global__ __launch_bounds__(256) void k_scatter(const int* __restrict__ rows, const int* __restrict__ cols,
    const float* __restrict__ nvals, int* __restrict__ curs,
    int* __restrict__ cols_s, float* __restrict__ vals_s){
  int e = blockIdx.x*256 + threadIdx.x;
  if (e < EE){
    int r = rows[e];
    int pos = atomicAdd(&curs[r], 1);
    cols_s[pos] = cols[e];
    vals_s[pos] = nvals[e];
  }
}

// ---------------- SpMM (wave per row, lane = feature, 4-way ILP) ----------------
__global__ __launch_bounds__(256) void k_spmm_bn(
    const int* __restrict__ offs, const int* __restrict__ cols_s, const float* __restrict__ vals_s,
    const float* __restrict__ xin, const float* __restrict__ scale, const float* __restrict__ shift,
    float* __restrict__ xout){
  int lane = threadIdx.x & 63;
  int r = blockIdx.x*4 + (threadIdx.x >> 6);
  float sc = scale[lane], sh = shift[lane];
  int b = offs[r], e = offs[r+1];
  float a0=0.f,a1=0.f,a2=0.f,a3=0.f;
  int j = b;
  for (; j+4<=e; j+=4){
    int c0=cols_s[j],c1=cols_s[j+1],c2=cols_s[j+2],c3=cols_s[j+3];
    float v0=vals_s[j],v1=vals_s[j+1],v2=vals_s[j+2],v3=vals_s[j+3];
    a0 += v0*(xin[(size_t)c0*FF+lane]*sc+sh);
    a1 += v1*(xin[(size_t)c1*FF+lane]*sc+sh);
    a2 += v2*(xin[(size_t)c2*FF+lane]*sc+sh);
    a3 += v3*(xin[(size_t)c3*FF+lane]*sc+sh);
  }
  for (; j<e; ++j) a0 += vals_s[j]*(xin[(size_t)cols_s[j]*FF+lane]*sc+sh);
  xout[(size_t)r*FF + lane] = (a0+a1)+(a2+a3);
}

__global__ __launch_bounds__(256) void k_spmm(
    const int* __restrict__ offs, const int* __restrict__ cols_s, const float* __restrict__ vals_s,
    const float* __restrict__ xin, float* __restrict__ xout){
  int lane = threadIdx.x & 63;
  int r = blockIdx.x*4 + (threadIdx.x >> 6);
  int b = offs[r], e = offs[r+1];
  float a0=0.f,a1=0.f,a2=0.f,a3=0.f;
  int j = b;
  for (; j+4<=e; j+=4){
    int c0=cols_s[j],c1=cols_s[j+1],c2=cols_s[j+2],c3=cols_s[j+3];
    float v0=vals_s[j],v1=vals_s[j+1],v2=vals_s[j+2],v3=vals_s[j+3];
    a0 += v0*xin[(size_t)c0*FF+lane];
    a1 += v1*xin[(size_t)c1*FF+lane];
    a2 += v2*xin[(size_t)c2*FF+lane];
    a3 += v3*xin[(size_t)c3*FF+lane];
  }
  for (; j<e; ++j) a0 += vals_s[j]*xin[(size_t)cols_s[j]*FF+lane];
  xout[(size_t)r*FF + lane] = (a0+a1)+(a2+a3);
}

// ---------------- s0 = softmax(relu(x_cov@W1+b1)@W2+b2), fused softmax ----------------
__global__ __launch_bounds__(256) void k_s0(
    const float* __restrict__ xcov,
    const float* __restrict__ W1, const float* __restrict__ b1,
    const float* __restrict__ W2, const float* __restrict__ b2,
    float* __restrict__ s0){
  __shared__ float xs[32][FF];      // 8K
  __shared__ float hs[32][132];     // padded: conflict-free per-lane-row reads, 16B-aligned f4
  __shared__ float chunk[32*HH];    // 16K, reused both layers
  int t = threadIdx.x; int r0 = blockIdx.x*32;
  for (int i=t;i<32*FF;i+=256){ int r=i>>6, f=i&63; int gr=r0+r; xs[r][f] = (gr<NN)? xcov[gr*FF+f] : 0.f; }
  __syncthreads();
  { // layer 1: h = relu(x@W1+b1); thread: col j=t&127, rows r=(t>>7)+2p
    int j = t & 127, rb = t >> 7;
    float acc[16]; float bb = b1[j];
    #pragma unroll
    for (int p=0;p<16;p++) acc[p] = bb;
    for (int kc=0;kc<2;kc++){
      for (int i=t;i<32*HH;i+=256) chunk[i] = W1[(kc*32 + (i>>7))*HH + (i&127)];
      __syncthreads();
      float cw[32];
      #pragma unroll
      for (int k=0;k<32;k++) cw[k] = chunk[k*HH + j];
      #pragma unroll
      for (int p=0;p<16;p++){
        int r = rb + 2*p;
        float a = acc[p];
        #pragma unroll
        for (int k4=0;k4<8;k4++){
          float4 xq = *(const float4*)&xs[r][kc*32 + k4*4];
          a += xq.x*cw[k4*4+0]; a += xq.y*cw[k4*4+1];
          a += xq.z*cw[k4*4+2]; a += xq.w*cw[k4*4+3];
        }
        acc[p] = a;
      }
      __syncthreads();
    }
    #pragma unroll
    for (int p=0;p<16;p++){ int r = rb + 2*p; hs[r][j] = fmaxf(acc[p], 0.f); }
  }
  __syncthreads();
  { // layer 2 + softmax: thread: row r=t>>3, lane l=t&7, cols j=l+8q
    int r = t >> 3, l = t & 7;
    float acc[13];
    #pragma unroll
    for (int q=0;q<13;q++){ int j = l + 8*q; acc[q] = (j < CC)? b2[j] : 0.f; }
    for (int kc=0;kc<4;kc++){
      for (int i=t;i<32*104;i+=256){ int kk=i/104, jj=i-kk*104; chunk[i] = (jj<CC)? W2[(kc*32+kk)*CC + jj] : 0.f; }
      __syncthreads();
      #pragma unroll
      for (int k4=0;k4<8;k4++){
        float4 hq = *(const float4*)&hs[r][kc*32 + k4*4];
        float hv[4] = {hq.x, hq.y, hq.z, hq.w};
        #pragma unroll
        for (int c=0;c<4;c++){
          float h = hv[c];
          const float* crow = &chunk[(k4*4+c)*104 + l];
          #pragma unroll
          for (int q=0;q<13;q++) acc[q] += h * crow[8*q];
        }
      }
      __syncthreads();
    }
    // softmax over the 8-lane group owning row r
    float mx = -1e30f;
    #pragma unroll
    for (int q=0;q<13;q++){ if (l + 8*q < CC) mx = fmaxf(mx, acc[q]); }
    #pragma unroll
    for (int o=1;o<8;o<<=1) mx = fmaxf(mx, __shfl_xor(mx, o));
    float sum = 0.f;
    #pragma unroll
    for (int q=0;q<13;q++){ if (l + 8*q < CC){ acc[q] = expf(acc[q]-mx); sum += acc[q]; } }
    #pragma unroll
    for (int o=1;o<8;o<<=1) sum += __shfl_xor(sum, o);
    int gr = r0 + r;
    if (gr < NN){
      float inv = 1.f/sum;
      #pragma unroll
      for (int q=0;q<13;q++){ int j = l + 8*q; if (j < CC) s0[(size_t)gr*CC + j] = acc[q]*inv; }
    }
  }
}

// ---------------- x_cov1 = s0^T @ x_cov (partials + atomic finish) ----------------
__global__ __launch_bounds__(256) void k_xcov1(
    const float* __restrict__ s0, const float* __restrict__ xcov, float* __restrict__ xc1){
  __shared__ float srow[4][CC];
  __shared__ float xrow[4][FF];
  int t = threadIdx.x;
  int rbase = blockIdx.x * 100;     // 100 blocks x 100 rows
  int f = t & 63, cb = (t>>6)*25;   // thread owns (c in [cb,cb+25), fixed f)
  float acc[25];
  #pragma unroll
  for (int i=0;i<25;i++) acc[i]=0.f;
  for (int step=0; step<25; ++step){
    int rr0 = rbase + step*4;
    for (int i=t;i<4*CC;i+=256){ int rr=i/CC; srow[rr][i - rr*CC] = s0[(size_t)(rr0+rr)*CC + (i - rr*CC)]; }
    for (int i=t;i<4*FF;i+=256){ int rr=i>>6; xrow[rr][i&63] = xcov[(size_t)(rr0+rr)*FF + (i&63)]; }
    __syncthreads();
    #pragma unroll
    for (int rr=0;rr<4;rr++){
      float xv = xrow[rr][f];
      #pragma unroll
      for (int i=0;i<25;i++) acc[i] += srow[rr][cb+i]*xv;
    }
    __syncthreads();
  }
  #pragma unroll
  for (int i=0;i<25;i++) atomicAdd(&xc1[(cb+i)*FF + f], acc[i]);
}

// ---------------- gv[f] = 2*sigmoid(fc[f] - colsum(x_cov1)[f]) ----------------
__global__ void k_gv(const float* __restrict__ xc1, const float* __restrict__ fc, float* __restrict__ gv){
  int f = threadIdx.x; // 64 threads
  float s = 0.f;
  for (int c=0;c<CC;c++) s += xc1[c*FF + f];
  float z = fc[f] - s;
  gv[f] = 2.f / (1.f + expf(-z));
}

// ---------------- dots: per-edge <s0[r],s0[c]>; s0 stays L2-hot (no big write stream) ----------------
__global__ __launch_bounds__(256) void k_dots(
    const int* __restrict__ rows, const int* __restrict__ cols,
    const float* __restrict__ s0, float* __restrict__ dotv){
  __shared__ int rs[256], cs[256];
  __shared__ float db[256];
  int t = threadIdx.x; int e0 = blockIdx.x*256;
  rs[t] = rows[e0+t]; cs[t] = cols[e0+t];
  __syncthreads();
  int g = t>>4, lane = t&15;        // 16 lanes per edge
  for (int it=0; it<16; ++it){
    int ed = g*16 + it;
    const float4* sr = (const float4*)(s0 + (size_t)rs[ed]*CC);   // 400B rows: 16B aligned
    const float4* sc = (const float4*)(s0 + (size_t)cs[ed]*CC);
    float4 a = sr[lane], b = sc[lane];
    float p = a.x*b.x + a.y*b.y + a.z*b.z + a.w*b.w;              // f4 0..15
    if (lane < 9){
      float4 a2 = sr[16+lane], b2 = sc[16+lane];                  // f4 16..24 (=100 floats)
      p += a2.x*b2.x + a2.y*b2.y + a2.z*b2.z + a2.w*b2.w;
    }
    #pragma unroll
    for (int o=1;o<16;o<<=1) p += __shfl_xor(p, o);
    if (lane==0) db[ed] = p;
  }
  __syncthreads();
  dotv[e0+t] = db[t];
}

// ---------------- adjs: streaming cumprod + LDS-transposed float4 write ----------------
__global__ __launch_bounds__(256) void k_adjs_stream(
    const float* __restrict__ dotv, const float* __restrict__ adjv,
    const float* __restrict__ gv, float* __restrict__ out){
  __shared__ float gvs[64];
  __shared__ float buf[16*258];     // [feature][edge+pad]
  int t = threadIdx.x;
  int e0 = blockIdx.x*256;
  if (t < 64) gvs[t] = gv[t];
  float dot = dotv[e0+t];
  float adj = adjv[e0+t];
  __syncthreads();
  float cum = 1.f;
  float4* out4 = (float4*)out;
  size_t obase4 = (size_t)e0*16;
  for (int ch=0; ch<4; ++ch){
    #pragma unroll
    for (int j=0;j<16;j++){
      cum *= dot * gvs[ch*16+j];    // sequential: matches reference cumprod rounding
      buf[j*258 + t] = adj*cum;
    }
    __syncthreads();
    #pragma unroll
    for (int i=0;i<4;i++){
      int id = i*256 + t;
      int el = id >> 2, f4 = id & 3;
      float4 v;
      v.x = buf[(f4*4+0)*258 + el];
      v.y = buf[(f4*4+1)*258 + el];
      v.z = buf[(f4*4+2)*258 + el];
      v.w = buf[(f4*4+3)*258 + el];
      out4[obase4 + (size_t)el*16 + ch*4 + f4] = v;
    }
    __syncthreads();
  }
}

// ---------------- MLP + log_softmax (fused epilogue) ----------------
__global__ __launch_bounds__(256) void k_mlp(
    const float* __restrict__ xin,
    const float* __restrict__ W1, const float* __restrict__ b1,
    const float* __restrict__ W2, const float* __restrict__ b2,
    const float* __restrict__ W3, const float* __restrict__ b3,
    const float* __restrict__ pa, float* __restrict__ out){
  __shared__ float xs[32][FF];
  __shared__ float h1[32][HH];
  __shared__ float h2[32][132];     // padded for final-stage per-lane-row f4 reads
  __shared__ float chunk[32*HH];
  __shared__ float w3s[HH*2];
  int t = threadIdx.x; int r0 = blockIdx.x*32;
  float a0 = pa[0];
  for (int i=t;i<32*FF;i+=256){ int r=i>>6,f=i&63; int gr=r0+r; xs[r][f]=(gr<NN)? xin[gr*FF+f] : 0.f; }
  for (int i=t;i<HH*2;i+=256) w3s[i] = W3[i];
  __syncthreads();
  { // h1 = prelu(x@W1+b1)
    int j = t & 127, rb = t >> 7;
    float acc[16]; float bb=b1[j];
    #pragma unroll
    for (int p=0;p<16;p++) acc[p]=bb;
    for (int kc=0;kc<2;kc++){
      for (int i=t;i<32*HH;i+=256) chunk[i]=W1[(kc*32+(i>>7))*HH+(i&127)];
      __syncthreads();
      float cw[32];
      #pragma unroll
      for (int k=0;k<32;k++) cw[k] = chunk[k*HH + j];
      #pragma unroll
      for (int p=0;p<16;p++){
        int r = rb + 2*p;
        float a = acc[p];
        #pragma unroll
        for (int k4=0;k4<8;k4++){
          float4 xq = *(const float4*)&xs[r][kc*32 + k4*4];
          a += xq.x*cw[k4*4+0]; a += xq.y*cw[k4*4+1];
          a += xq.z*cw[k4*4+2]; a += xq.w*cw[k4*4+3];
        }
        acc[p] = a;
      }
      __syncthreads();
    }
    #pragma unroll
    for (int p=0;p<16;p++){ int r=rb+2*p; float v=acc[p]; h1[r][j] = v>0.f? v : a0*v; }
  }
  __syncthreads();
  { // h2 = prelu(h1@W2+b2)
    int j = t & 127, rb = t >> 7;
    float acc[16]; float bb=b2[j];
    #pragma unroll
    for (int p=0;p<16;p++) acc[p]=bb;
    for (int kc=0;kc<4;kc++){
      for (int i=t;i<32*HH;i+=256) chunk[i]=W2[(kc*32+(i>>7))*HH+(i&127)];
      __syncthreads();
      float cw[32];
      #pragma unroll
      for (int k=0;k<32;k++) cw[k] = chunk[k*HH + j];
      #pragma unroll
      for (int p=0;p<16;p++){
        int r = rb + 2*p;
        float a = acc[p];
        #pragma unroll
        for (int k4=0;k4<8;k4++){
          float4 xq = *(const float4*)&h1[r][kc*32 + k4*4];
          a += xq.x*cw[k4*4+0]; a += xq.y*cw[k4*4+1];
          a += xq.z*cw[k4*4+2]; a += xq.w*cw[k4*4+3];
        }
        acc[p] = a;
      }
      __syncthreads();
    }
    #pragma unroll
    for (int p=0;p<16;p++){ int r=rb+2*p; float v=acc[p]; h2[r][t&127] = v>0.f? v : a0*v; }
  }
  __syncthreads();
  { // logits + log_softmax: row r=t>>3, lane l=t&7 owns k=l*16..l*16+15
    int r = t >> 3, l = t & 7;
    float aA = 0.f, aB = 0.f;
    #pragma unroll
    for (int n=0;n<4;n++){
      float4 hq = *(const float4*)&h2[r][l*16 + n*4];
      int kb = l*16 + n*4;
      aA += hq.x*w3s[(kb+0)*2+0]; aB += hq.x*w3s[(kb+0)*2+1];
      aA += hq.y*w3s[(kb+1)*2+0]; aB += hq.y*w3s[(kb+1)*2+1];
      aA += hq.z*w3s[(kb+2)*2+0]; aB += hq.z*w3s[(kb+2)*2+1];
      aA += hq.w*w3s[(kb+3)*2+0]; aB += hq.w*w3s[(kb+3)*2+1];
    }
    #pragma unroll
    for (int o=1;o<8;o<<=1){ aA += __shfl_xor(aA,o); aB += __shfl_xor(aB,o); }
    int gr = r0 + r;
    if (l==0 && gr < NN){
      float l0 = aA + b3[0], l1 = aB + b3[1];
      float m = fmaxf(l0,l1);
      float lse = m + logf(expf(l0-m)+expf(l1-m));
      out[gr*2+0] = l0 - lse;
      out[gr*2+1] = l1 - lse;
    }
  }
}

extern "C" void kernel_launch(void* const* d_in, const int* in_sizes, int n_in,
                              void* d_out, int out_size, void* d_ws, size_t ws_size,
                              hipStream_t stream) {
  (void)in_sizes; (void)n_in; (void)out_size; (void)ws_size;
  const float* x      = (const float*)d_in[0];
  const float* xcov   = (const float*)d_in[1];
  const int*   ei     = (const int*)d_in[2];
  const float* adjv   = (const float*)d_in[3];
  const float* nvals  = (const float*)d_in[4];
  const float* fc     = (const float*)d_in[5];
  const float* gamma  = (const float*)d_in[6];
  const float* beta   = (const float*)d_in[7];
  const float* p0W1   = (const float*)d_in[8];
  const float* p0b1   = (const float*)d_in[9];
  const float* p0W2   = (const float*)d_in[10];
  const float* p0b2   = (const float*)d_in[11];
  // d_in[12..15]: pool1 weights — mathematically dead (softmax over 1 class == 1)
  const float* mW1    = (const float*)d_in[16];
  const float* mb1    = (const float*)d_in[17];
  const float* mW2    = (const float*)d_in[18];
  const float* mb2    = (const float*)d_in[19];
  const float* mW3    = (const float*)d_in[20];
  const float* mb3    = (const float*)d_in[21];
  const float* pa     = (const float*)d_in[22];
  const int* rows = ei;
  const int* cols = ei + EE;
  float* out = (float*)d_out;

  char* w = (char*)d_ws;
  auto alloc = [&](size_t bytes)->void*{ void* p=(void*)w; w += (bytes + 255) & ~(size_t)255; return p; };
  float*  S0    = (float*)alloc(sizeof(float)*(size_t)NN*CC);   // 4 MB
  float*  XC1   = (float*)alloc(sizeof(float)*CC*FF);
  float*  GV    = (float*)alloc(sizeof(float)*FF);
  float*  SCALE = (float*)alloc(sizeof(float)*FF);
  float*  SHIFT = (float*)alloc(sizeof(float)*FF);
  float*  XA    = (float*)alloc(sizeof(float)*(size_t)NN*FF);
  float*  XB    = (float*)alloc(sizeof(float)*(size_t)NN*FF);
  int*    COUNTS= (int*)alloc(sizeof(int)*NN);
  int*    OFFS  = (int*)alloc(sizeof(int)*(NN+1));
  int*    CURS  = (int*)alloc(sizeof(int)*NN);
  int*    COLS_S= (int*)alloc(sizeof(int)*EE);
  float*  VALS_S= (float*)alloc(sizeof(float)*EE);
  float*  DOTV  = (float*)alloc(sizeof(float)*EE);
  double* BNP   = (double*)alloc(sizeof(double)*100*128);

  hipMemsetAsync(COUNTS, 0, sizeof(int)*NN, stream);
  hipMemsetAsync(XC1, 0, sizeof(float)*CC*FF, stream);

  k_bn_partial<<<100, 256, 0, stream>>>(x, BNP);
  k_bn_finish<<<1, 64, 0, stream>>>(BNP, gamma, beta, SCALE, SHIFT);
  k_hist<<<EE/256, 256, 0, stream>>>(rows, COUNTS);
  k_scan<<<1, 1024, 0, stream>>>(COUNTS, OFFS, CURS);
  k_scatter<<<EE/256, 256, 0, stream>>>(rows, cols, nvals, CURS, COLS_S, VALS_S);

  k_s0<<<(NN+31)/32, 256, 0, stream>>>(xcov, p0W1, p0b1, p0W2, p0b2, S0);
  k_dots<<<EE/256, 256, 0, stream>>>(rows, cols, S0, DOTV);
  k_xcov1<<<100, 256, 0, stream>>>(S0, xcov, XC1);
  k_gv<<<1, 64, 0, stream>>>(XC1, fc, GV);
  k_adjs_stream<<<EE/256, 256, 0, stream>>>(DOTV, adjv, GV, out + 2*NN);

  k_spmm_bn<<<NN/4, 256, 0, stream>>>(OFFS, COLS_S, VALS_S, x, SCALE, SHIFT, XA);
  k_spmm   <<<NN/4, 256, 0, stream>>>(OFFS, COLS_S, VALS_S, XA, XB);
  k_spmm   <<<NN/4, 256, 0, stream>>>(OFFS, COLS_S, VALS_S, XB, XA);

  k_mlp<<<(NN+31)/32, 256, 0, stream>>>(XA, mW1, mb1, mW2, mb2, mW3, mb3, pa, out);
}